// Round 2
// baseline (358.496 us; speedup 1.0000x reference)
//
#include <hip/hip_runtime.h>

// x:   [B=8, C=16, H=512, W=512] f32; phi: [B=8, 2, H, W] f32 (dy, dx); out: [B,C,H,W] f32
// Bilinear pull, wrap boundary (H,W pow2 -> & (N-1)).
// Key optimization: horizontal tap pairs (v00,v01) and (v10,v11) share a cache line
// 15/16 of the time -> load them as one (possibly unaligned) dwordx2 to halve the
// scattered-gather line-touch cost in the TA/TCP pipe (measured bottleneck: 56 cyc per
// scattered gather instr, VALUBusy 7%, HBM 30% of peak).

constexpr int B = 8, C = 16, H = 512, W = 512;
constexpr int HW = H * W;

typedef float f2u __attribute__((ext_vector_type(2), aligned(4)));

__global__ __launch_bounds__(256) void pull_wrap_kernel(const float* __restrict__ x,
                                                        const float* __restrict__ phi,
                                                        float* __restrict__ out) {
    int idx = blockIdx.x * blockDim.x + threadIdx.x;  // over B*H*W (exact multiple of 256)
    int b  = idx >> 18;            // / (512*512)
    int hw = idx & (HW - 1);
    int h  = hw >> 9;              // / 512
    int w  = hw & (W - 1);

    const float* phib = phi + (size_t)b * 2 * HW;
    float cy = phib[hw]      + (float)h;   // dy + y
    float cx = phib[HW + hw] + (float)w;   // dx + x

    float y0f = floorf(cy);
    float x0f = floorf(cx);
    float wy  = cy - y0f;
    float wx  = cx - x0f;

    int y0 = ((int)y0f) & (H - 1);
    int x0 = ((int)x0f) & (W - 1);
    int y1 = (y0 + 1)   & (H - 1);

    int o00 = y0 * W + x0;
    int o10 = y1 * W + x0;

    float omwx = 1.0f - wx;
    float omwy = 1.0f - wy;

    const float* plane = x   + (size_t)b * C * HW;
    float*       outp  = out + (size_t)b * C * HW + hw;

    if (x0 < W - 1) {
        // fast path: (x0, x0+1) contiguous -> one 8B load per tap row
#pragma unroll
        for (int c = 0; c < C; ++c) {
            f2u t  = *(const f2u*)(plane + o00);   // {v00, v01}
            f2u bo = *(const f2u*)(plane + o10);   // {v10, v11}
            float top = t.x  * omwx + t.y  * wx;
            float bot = bo.x * omwx + bo.y * wx;
            __builtin_nontemporal_store(top * omwy + bot * wy, outp + (size_t)c * HW);
            plane += HW;
        }
    } else {
        // rare path (x0 == 511): v01/v11 wrap to column 0; avoids the one OOB pair
        // at the very last element of x.
        int o01 = y0 * W;
        int o11 = y1 * W;
#pragma unroll
        for (int c = 0; c < C; ++c) {
            float v00 = plane[o00];
            float v01 = plane[o01];
            float v10 = plane[o10];
            float v11 = plane[o11];
            float top = v00 * omwx + v01 * wx;
            float bot = v10 * omwx + v11 * wx;
            __builtin_nontemporal_store(top * omwy + bot * wy, outp + (size_t)c * HW);
            plane += HW;
        }
    }
}

extern "C" void kernel_launch(void* const* d_in, const int* in_sizes, int n_in,
                              void* d_out, int out_size, void* d_ws, size_t ws_size,
                              hipStream_t stream) {
    const float* x   = (const float*)d_in[0];
    const float* phi = (const float*)d_in[1];
    float* out = (float*)d_out;

    int n = B * HW;
    dim3 block(256);
    dim3 grid((n + 255) / 256);
    pull_wrap_kernel<<<grid, block, 0, stream>>>(x, phi, out);
}